// Round 1
// baseline (4396.748 us; speedup 1.0000x reference)
//
#include <hip/hip_runtime.h>
#include <math.h>

#define NN 20000     // nodes
#define NE 320000    // edges
#define HD 256       // hidden dim
#define EDIM 64      // edge feature dim
#define DIN 576      // 2H + ED

// LDS padded strides (floats)
#define APAD 36      // for [16][32] A tiles and [256][32] hidT
#define BPAD 260     // for [16][256] B tiles
#define GBPAD 204    // 3 chunks * 68

#define FMA4(accp, a, b) \
  do { (accp)[0] += (a)*(b).x; (accp)[1] += (a)*(b).y; \
       (accp)[2] += (a)*(b).z; (accp)[3] += (a)*(b).w; } while (0)

// -------------------- fused edge MLP + scatter-add --------------------
// block: 256 threads, BM=32 edges. thread (ty=t>>4, tx=t&15) owns
// edges e = ty*2+{0,1}, cols c = tx*4 + 64*j + jj (j=0..3, jj=0..3).
__global__ __launch_bounds__(256) void edge_kernel(
    const float* __restrict__ h, const int* __restrict__ ei,
    const float* __restrict__ eattr,
    const float* __restrict__ W1, const float* __restrict__ b1,
    const float* __restrict__ W2, const float* __restrict__ b2,
    float* __restrict__ agg)
{
  __shared__ float A_lds[16][APAD];     // [k][edge]
  __shared__ float B_lds[16][BPAD];     // [k][col]  (W^T tile)
  __shared__ float hidT[HD][APAD];      // [hid_col][edge]
  __shared__ int rowL[32], colL[32];

  const int t  = threadIdx.x;
  const int tx = t & 15, ty = t >> 4;
  const int e0 = blockIdx.x * 32;
  const int ks = t & 15;     // staging k
  const int qs = t >> 4;     // staging group 0..15

  if (t < 32) {
    rowL[t] = ei[e0 + t];
    colL[t] = ei[NE + e0 + t];
  }

  float acc1[2][16];
#pragma unroll
  for (int i = 0; i < 2; ++i)
#pragma unroll
    for (int j = 0; j < 16; ++j) acc1[i][j] = 0.f;

  // ---------------- layer 1: K = 576 in 36 tiles of 16 ----------------
  for (int kb = 0; kb < 36; ++kb) {
    const int k0 = kb * 16;
    __syncthreads();
    // stage A (gathered edge_in): regions are 16-aligned so branch is tile-uniform
    {
      const int kk = k0 + ks;
#pragma unroll
      for (int half = 0; half < 2; ++half) {
        const int e = qs + half * 16;
        float v;
        if (kk < 256)       v = h[(size_t)rowL[e] * HD + kk];
        else if (kk < 512)  v = h[(size_t)colL[e] * HD + (kk - 256)];
        else                v = eattr[(size_t)(e0 + e) * EDIM + (kk - 512)];
        A_lds[ks][e] = v;
      }
    }
    // stage B = W1^T tile: B[k][n] = W1[n][k0+k]
#pragma unroll
    for (int i = 0; i < 16; ++i) {
      const int n = i * 16 + qs;
      B_lds[ks][n] = W1[(size_t)n * DIN + k0 + ks];
    }
    __syncthreads();
#pragma unroll
    for (int k = 0; k < 16; ++k) {
      const float2 a = *(const float2*)&A_lds[k][ty * 2];
#pragma unroll
      for (int j = 0; j < 4; ++j) {
        const float4 b = *(const float4*)&B_lds[k][tx * 4 + 64 * j];
        FMA4(&acc1[0][j * 4], a.x, b);
        FMA4(&acc1[1][j * 4], a.y, b);
      }
    }
  }

  // ---------------- hidden = relu(. + b1), store transposed ----------------
#pragma unroll
  for (int j = 0; j < 4; ++j)
#pragma unroll
    for (int jj = 0; jj < 4; ++jj) {
      const int c = tx * 4 + 64 * j + jj;
      const float bb = b1[c];
      float v0 = acc1[0][j * 4 + jj] + bb; v0 = v0 > 0.f ? v0 : 0.f;
      float v1 = acc1[1][j * 4 + jj] + bb; v1 = v1 > 0.f ? v1 : 0.f;
      *(float2*)&hidT[c][ty * 2] = make_float2(v0, v1);
    }

  // ---------------- layer 2: K = 256 in 16 tiles of 16 ----------------
  float acc2[2][16];
#pragma unroll
  for (int i = 0; i < 2; ++i)
#pragma unroll
    for (int j = 0; j < 16; ++j) acc2[i][j] = 0.f;

  for (int kb = 0; kb < 16; ++kb) {
    const int k0 = kb * 16;
    __syncthreads();   // hidT writes + previous B use complete
#pragma unroll
    for (int i = 0; i < 16; ++i) {
      const int n = i * 16 + qs;
      B_lds[ks][n] = W2[(size_t)n * HD + k0 + ks];
    }
    __syncthreads();
#pragma unroll
    for (int k = 0; k < 16; ++k) {
      const float2 a = *(const float2*)&hidT[k0 + k][ty * 2];
#pragma unroll
      for (int j = 0; j < 4; ++j) {
        const float4 b = *(const float4*)&B_lds[k][tx * 4 + 64 * j];
        FMA4(&acc2[0][j * 4], a.x, b);
        FMA4(&acc2[1][j * 4], a.y, b);
      }
    }
  }

  // ---------------- scatter-add msg + b2 into agg ----------------
#pragma unroll
  for (int i = 0; i < 2; ++i) {
    float* aggRow = agg + (size_t)rowL[ty * 2 + i] * HD;
#pragma unroll
    for (int j = 0; j < 4; ++j)
#pragma unroll
      for (int jj = 0; jj < 4; ++jj) {
        const int c = tx * 4 + 64 * j + jj;
        unsafeAtomicAdd(&aggRow[c], acc2[i][j * 4 + jj] + b2[c]);
      }
  }
}

// -------------------- fused GRU update --------------------
// block: 32 nodes x 64 h-cols; 6 gate tiles kept in registers.
__global__ __launch_bounds__(256) void gru_kernel(
    const float* __restrict__ h, const float* __restrict__ agg,
    const float* __restrict__ W_ih, const float* __restrict__ b_ih,
    const float* __restrict__ W_hh, const float* __restrict__ b_hh,
    float* __restrict__ out)
{
  __shared__ float Aagg[16][APAD];
  __shared__ float Ah[16][APAD];
  __shared__ float Bih[16][GBPAD];   // [k][chunk*68 + c]
  __shared__ float Bhh[16][GBPAD];

  const int t  = threadIdx.x;
  const int tx = t & 15, ty = t >> 4;
  const int nb = blockIdx.x * 32;
  const int cb = blockIdx.y * 64;
  const int ks = t & 15, qs = t >> 4;

  float accI[3][2][4], accH[3][2][4];
#pragma unroll
  for (int ch = 0; ch < 3; ++ch)
#pragma unroll
    for (int i = 0; i < 2; ++i)
#pragma unroll
      for (int jj = 0; jj < 4; ++jj) { accI[ch][i][jj] = 0.f; accH[ch][i][jj] = 0.f; }

  for (int kb = 0; kb < 16; ++kb) {
    const int k0 = kb * 16;
    __syncthreads();
#pragma unroll
    for (int half = 0; half < 2; ++half) {
      const int m = qs + half * 16;
      Aagg[ks][m] = agg[(size_t)(nb + m) * HD + k0 + ks];
      Ah[ks][m]   = h[(size_t)(nb + m) * HD + k0 + ks];
    }
#pragma unroll
    for (int i = 0; i < 12; ++i) {
      const int q = i * 16 + qs;        // 0..191
      const int chunk = q >> 6, c = q & 63;
      const int jrow = chunk * HD + cb + c;
      Bih[ks][chunk * 68 + c] = W_ih[(size_t)jrow * HD + k0 + ks];
      Bhh[ks][chunk * 68 + c] = W_hh[(size_t)jrow * HD + k0 + ks];
    }
    __syncthreads();
#pragma unroll
    for (int k = 0; k < 16; ++k) {
      const float2 aA = *(const float2*)&Aagg[k][ty * 2];
      const float2 aH = *(const float2*)&Ah[k][ty * 2];
#pragma unroll
      for (int ch = 0; ch < 3; ++ch) {
        const float4 bI = *(const float4*)&Bih[k][ch * 68 + tx * 4];
        const float4 bH = *(const float4*)&Bhh[k][ch * 68 + tx * 4];
        FMA4(&accI[ch][0][0], aA.x, bI);
        FMA4(&accI[ch][1][0], aA.y, bI);
        FMA4(&accH[ch][0][0], aH.x, bH);
        FMA4(&accH[ch][1][0], aH.y, bH);
      }
    }
  }

#pragma unroll
  for (int i = 0; i < 2; ++i) {
    const int n = nb + ty * 2 + i;
#pragma unroll
    for (int jj = 0; jj < 4; ++jj) {
      const int c = cb + tx * 4 + jj;
      const float xr = accI[0][i][jj] + b_ih[c];
      const float xz = accI[1][i][jj] + b_ih[c + HD];
      const float xn = accI[2][i][jj] + b_ih[c + 2 * HD];
      const float hr = accH[0][i][jj] + b_hh[c];
      const float hz = accH[1][i][jj] + b_hh[c + HD];
      const float hn = accH[2][i][jj] + b_hh[c + 2 * HD];
      const float r  = 1.f / (1.f + __expf(-(xr + hr)));
      const float z  = 1.f / (1.f + __expf(-(xz + hz)));
      const float ng = tanhf(xn + r * hn);
      const float hv = h[(size_t)n * HD + c];
      out[(size_t)n * HD + c] = (1.f - z) * ng + z * hv;
    }
  }
}

extern "C" void kernel_launch(void* const* d_in, const int* in_sizes, int n_in,
                              void* d_out, int out_size, void* d_ws, size_t ws_size,
                              hipStream_t stream)
{
  const float* h     = (const float*)d_in[0];
  const int*   ei    = (const int*)d_in[1];
  const float* eattr = (const float*)d_in[2];
  const float* W1    = (const float*)d_in[3];
  const float* b1    = (const float*)d_in[4];
  const float* W2    = (const float*)d_in[5];
  const float* b2    = (const float*)d_in[6];
  const float* W_ih  = (const float*)d_in[7];
  const float* b_ih  = (const float*)d_in[8];
  const float* W_hh  = (const float*)d_in[9];
  const float* b_hh  = (const float*)d_in[10];
  float* out = (float*)d_out;
  float* agg = (float*)d_ws;   // [NN][HD] f32 = 20.5 MB

  hipMemsetAsync(agg, 0, (size_t)NN * HD * sizeof(float), stream);
  edge_kernel<<<NE / 32, 256, 0, stream>>>(h, ei, eattr, W1, b1, W2, b2, agg);
  gru_kernel<<<dim3(NN / 32, HD / 64), 256, 0, stream>>>(h, agg, W_ih, b_ih, W_hh, b_hh, out);
}

// Round 3
// 1363.716 us; speedup vs baseline: 3.2241x; 3.2241x over previous
//
#include <hip/hip_runtime.h>
#include <math.h>

#define NN 20000     // nodes
#define NE 320000    // edges
#define HD 256       // hidden dim
#define EDIM 64      // edge feature dim
#define DIN 576      // 2H + ED

#define ASTRIDE 584  // layer-1 LDS A row stride in halves (pad: 2-way bank alias = free)
#define HSTRIDE 264  // hid LDS row stride in halves

typedef __attribute__((ext_vector_type(4))) _Float16 h4;
typedef __attribute__((ext_vector_type(8))) _Float16 h8;
typedef __attribute__((ext_vector_type(4))) float f32x4;

// fp16 copies of the weights, original [n][k] row-major layout
__device__ _Float16 g_W1h[HD * DIN];
__device__ _Float16 g_W2h[HD * HD];

__device__ __forceinline__ h4 f2h4(float4 v) {
  return (h4){(_Float16)v.x, (_Float16)v.y, (_Float16)v.z, (_Float16)v.w};
}

// -------------------- weight f32 -> fp16 conversion --------------------
__global__ __launch_bounds__(256) void cvt_kernel(const float* __restrict__ W1,
                                                  const float* __restrict__ W2) {
  const int idx = blockIdx.x * 256 + threadIdx.x;   // float4 index
  const int n1 = HD * DIN / 4;                      // 36864
  const int n2 = HD * HD / 4;                       // 16384
  if (idx < n1) {
    float4 v = ((const float4*)W1)[idx];
    *(h4*)&g_W1h[idx * 4] = f2h4(v);
  } else if (idx < n1 + n2) {
    const int j = idx - n1;
    float4 v = ((const float4*)W2)[j];
    *(h4*)&g_W2h[j * 4] = f2h4(v);
  }
}

// -------------------- fused edge MLP (MFMA fp16) + scatter-add --------------------
// 64 edges/block, 4 waves; wave w owns edge rows 16w..16w+15, all 256 cols.
__global__ __launch_bounds__(256, 2) void edge_kernel(
    const float* __restrict__ h, const int* __restrict__ ei,
    const float* __restrict__ eattr,
    const float* __restrict__ b1, const float* __restrict__ b2,
    float* __restrict__ agg)
{
  __shared__ _Float16 A[64 * ASTRIDE];   // 74752 B; reused for hid[64][HSTRIDE]
  __shared__ int rowL[64], colL[64];

  const int t   = threadIdx.x;
  const int w   = t >> 6;       // wave 0..3
  const int l   = t & 63;       // lane
  const int l15 = l & 15;
  const int lg  = l >> 4;       // lane group 0..3
  const int e0  = blockIdx.x * 64;

  if (t < 64) { rowL[t] = ei[e0 + t]; colL[t] = ei[NE + e0 + t]; }
  __syncthreads();

  // ---- stage edge_in[64][576] as fp16 into LDS (coalesced: 1 row per wave-instr) ----
#pragma unroll
  for (int i = 0; i < 16; ++i) {                  // h[row] part, k=0..255
    const int e = i * 4 + w;
    float4 v = ((const float4*)(h + (size_t)rowL[e] * HD))[l];
    *(h4*)&A[e * ASTRIDE + l * 4] = f2h4(v);
  }
#pragma unroll
  for (int i = 0; i < 16; ++i) {                  // h[col] part, k=256..511
    const int e = i * 4 + w;
    float4 v = ((const float4*)(h + (size_t)colL[e] * HD))[l];
    *(h4*)&A[e * ASTRIDE + 256 + l * 4] = f2h4(v);
  }
#pragma unroll
  for (int i = 0; i < 4; ++i) {                   // edge_attr part, k=512..575
    const int e = i * 16 + w * 4 + lg;
    const int p = l & 15;
    float4 v = ((const float4*)(eattr + (size_t)(e0 + e) * EDIM))[p];
    *(h4*)&A[e * ASTRIDE + 512 + p * 4] = f2h4(v);
  }
  __syncthreads();

  // ---- layer 1: [64,576] @ W1^T -> acc (f32), 18 K-steps of 32 ----
  f32x4 acc[16];
#pragma unroll
  for (int nf = 0; nf < 16; ++nf) acc[nf] = (f32x4){0.f, 0.f, 0.f, 0.f};

  const int arow = (w * 16 + l15) * ASTRIDE + lg * 8;
  for (int ks = 0; ks < 18; ++ks) {
    const h8 a = *(const h8*)&A[arow + ks * 32];
#pragma unroll
    for (int nf = 0; nf < 16; ++nf) {
      const h8 b = *(const h8*)&g_W1h[(nf * 16 + l15) * DIN + ks * 32 + lg * 8];
      acc[nf] = __builtin_amdgcn_mfma_f32_16x16x32_f16(a, b, acc[nf], 0, 0, 0);
    }
  }

  // ---- hidden = relu(acc + b1) -> LDS fp16 (reuse A buffer) ----
  __syncthreads();   // everyone done reading A
#pragma unroll
  for (int nf = 0; nf < 16; ++nf) {
    const int c = nf * 16 + l15;
    const float bb = b1[c];
#pragma unroll
    for (int r = 0; r < 4; ++r) {
      const int e = w * 16 + lg * 4 + r;          // C/D: col=lane&15, row=(lane>>4)*4+r
      float v = acc[nf][r] + bb;
      v = v > 0.f ? v : 0.f;
      A[e * HSTRIDE + c] = (_Float16)v;
    }
  }
  __syncthreads();

  // ---- layer 2: [64,256] @ W2^T, 8 K-steps ----
  f32x4 acc2[16];
#pragma unroll
  for (int nf = 0; nf < 16; ++nf) acc2[nf] = (f32x4){0.f, 0.f, 0.f, 0.f};

  const int hrow = (w * 16 + l15) * HSTRIDE + lg * 8;
  for (int ks = 0; ks < 8; ++ks) {
    const h8 a = *(const h8*)&A[hrow + ks * 32];
#pragma unroll
    for (int nf = 0; nf < 16; ++nf) {
      const h8 b = *(const h8*)&g_W2h[(nf * 16 + l15) * HD + ks * 32 + lg * 8];
      acc2[nf] = __builtin_amdgcn_mfma_f32_16x16x32_f16(a, b, acc2[nf], 0, 0, 0);
    }
  }

  // ---- scatter-add msg + b2 into agg ----
#pragma unroll
  for (int nf = 0; nf < 16; ++nf) {
    const int c = nf * 16 + l15;
    const float bb = b2[c];
#pragma unroll
    for (int r = 0; r < 4; ++r) {
      const int e = w * 16 + lg * 4 + r;
      unsafeAtomicAdd(&agg[(size_t)rowL[e] * HD + c], acc2[nf][r] + bb);
    }
  }
}

// -------------------- fused GRU update (f32, unchanged) --------------------
#define APAD 36
#define GBPAD 204

#define FMA4(accp, a, b) \
  do { (accp)[0] += (a)*(b).x; (accp)[1] += (a)*(b).y; \
       (accp)[2] += (a)*(b).z; (accp)[3] += (a)*(b).w; } while (0)

__global__ __launch_bounds__(256) void gru_kernel(
    const float* __restrict__ h, const float* __restrict__ agg,
    const float* __restrict__ W_ih, const float* __restrict__ b_ih,
    const float* __restrict__ W_hh, const float* __restrict__ b_hh,
    float* __restrict__ out)
{
  __shared__ float Aagg[16][APAD];
  __shared__ float Ah[16][APAD];
  __shared__ float Bih[16][GBPAD];
  __shared__ float Bhh[16][GBPAD];

  const int t  = threadIdx.x;
  const int tx = t & 15, ty = t >> 4;
  const int nb = blockIdx.x * 32;
  const int cb = blockIdx.y * 64;
  const int ks = t & 15, qs = t >> 4;

  float accI[3][2][4], accH[3][2][4];
#pragma unroll
  for (int ch = 0; ch < 3; ++ch)
#pragma unroll
    for (int i = 0; i < 2; ++i)
#pragma unroll
      for (int jj = 0; jj < 4; ++jj) { accI[ch][i][jj] = 0.f; accH[ch][i][jj] = 0.f; }

  for (int kb = 0; kb < 16; ++kb) {
    const int k0 = kb * 16;
    __syncthreads();
#pragma unroll
    for (int half = 0; half < 2; ++half) {
      const int m = qs + half * 16;
      Aagg[ks][m] = agg[(size_t)(nb + m) * HD + k0 + ks];
      Ah[ks][m]   = h[(size_t)(nb + m) * HD + k0 + ks];
    }
#pragma unroll
    for (int i = 0; i < 12; ++i) {
      const int q = i * 16 + qs;
      const int chunk = q >> 6, c = q & 63;
      const int jrow = chunk * HD + cb + c;
      Bih[ks][chunk * 68 + c] = W_ih[(size_t)jrow * HD + k0 + ks];
      Bhh[ks][chunk * 68 + c] = W_hh[(size_t)jrow * HD + k0 + ks];
    }
    __syncthreads();
#pragma unroll
    for (int k = 0; k < 16; ++k) {
      const float2 aA = *(const float2*)&Aagg[k][ty * 2];
      const float2 aH = *(const float2*)&Ah[k][ty * 2];
#pragma unroll
      for (int ch = 0; ch < 3; ++ch) {
        const float4 bI = *(const float4*)&Bih[k][ch * 68 + tx * 4];
        const float4 bH = *(const float4*)&Bhh[k][ch * 68 + tx * 4];
        FMA4(&accI[ch][0][0], aA.x, bI);
        FMA4(&accI[ch][1][0], aA.y, bI);
        FMA4(&accH[ch][0][0], aH.x, bH);
        FMA4(&accH[ch][1][0], aH.y, bH);
      }
    }
  }

#pragma unroll
  for (int i = 0; i < 2; ++i) {
    const int n = nb + ty * 2 + i;
#pragma unroll
    for (int jj = 0; jj < 4; ++jj) {
      const int c = cb + tx * 4 + jj;
      const float xr = accI[0][i][jj] + b_ih[c];
      const float xz = accI[1][i][jj] + b_ih[c + HD];
      const float xn = accI[2][i][jj] + b_ih[c + 2 * HD];
      const float hr = accH[0][i][jj] + b_hh[c];
      const float hz = accH[1][i][jj] + b_hh[c + HD];
      const float hn = accH[2][i][jj] + b_hh[c + 2 * HD];
      const float r  = 1.f / (1.f + __expf(-(xr + hr)));
      const float z  = 1.f / (1.f + __expf(-(xz + hz)));
      const float ng = tanhf(xn + r * hn);
      const float hv = h[(size_t)n * HD + c];
      out[(size_t)n * HD + c] = (1.f - z) * ng + z * hv;
    }
  }
}

extern "C" void kernel_launch(void* const* d_in, const int* in_sizes, int n_in,
                              void* d_out, int out_size, void* d_ws, size_t ws_size,
                              hipStream_t stream)
{
  const float* h     = (const float*)d_in[0];
  const int*   ei    = (const int*)d_in[1];
  const float* eattr = (const float*)d_in[2];
  const float* W1    = (const float*)d_in[3];
  const float* b1    = (const float*)d_in[4];
  const float* W2    = (const float*)d_in[5];
  const float* b2    = (const float*)d_in[6];
  const float* W_ih  = (const float*)d_in[7];
  const float* b_ih  = (const float*)d_in[8];
  const float* W_hh  = (const float*)d_in[9];
  const float* b_hh  = (const float*)d_in[10];
  float* out = (float*)d_out;
  float* agg = (float*)d_ws;   // [NN][HD] f32 = 20.5 MB

  hipMemsetAsync(agg, 0, (size_t)NN * HD * sizeof(float), stream);
  cvt_kernel<<<(HD * DIN / 4 + HD * HD / 4 + 255) / 256, 256, 0, stream>>>(W1, W2);
  edge_kernel<<<NE / 64, 256, 0, stream>>>(h, ei, eattr, b1, b2, agg);
  gru_kernel<<<dim3(NN / 32, HD / 64), 256, 0, stream>>>(h, agg, W_ih, b_ih, W_hh, b_hh, out);
}

// Round 4
// 481.848 us; speedup vs baseline: 9.1248x; 2.8302x over previous
//
#include <hip/hip_runtime.h>
#include <math.h>

#define NN 20000     // nodes
#define NE 320000    // edges
#define HD 256       // hidden dim
#define EDIM 64      // edge feature dim
#define DIN 576      // 2H + ED

#define ASTRIDE 264  // LDS row stride in halves (264*2=528B -> 4-bank rotation, 2-way free)

typedef __attribute__((ext_vector_type(4))) _Float16 h4;
typedef __attribute__((ext_vector_type(8))) _Float16 h8;
typedef __attribute__((ext_vector_type(4))) float f32x4;

// fragment-ordered fp16 weights:
//   frag(cf, ks, l, j) = W[cf*16 + (l&15)][ks*32 + (l>>4)*8 + j]
__device__ _Float16 g_W1f[16 * 18 * 64 * 8];   // edge layer1: [cf][ksg<18][l][8]
__device__ _Float16 g_W2f[16 * 8  * 64 * 8];   // edge layer2
__device__ _Float16 g_Wrzf[32 * 16 * 64 * 8];  // GRU r,z combined K=512
__device__ _Float16 g_Wnxf[16 * 8  * 64 * 8];  // GRU n-gate, x side
__device__ _Float16 g_Wnhf[16 * 8  * 64 * 8];  // GRU n-gate, h side

__device__ __forceinline__ h4 f2h4(float4 v) {
  return (h4){(_Float16)v.x, (_Float16)v.y, (_Float16)v.z, (_Float16)v.w};
}

// -------------------- weight repack to fragment order --------------------
// one 64-lane group per fragment; groups: W1f 288 | W2f 128 | Wrz 512 | Wnx 128 | Wnh 128
__global__ __launch_bounds__(256) void cvt_kernel(
    const float* __restrict__ W1, const float* __restrict__ W2,
    const float* __restrict__ W_ih, const float* __restrict__ W_hh)
{
  const int idx = blockIdx.x * 256 + threadIdx.x;
  const int g = idx >> 6, l = idx & 63;
  const int r16 = l & 15, koff = (l >> 4) * 8;
  if (g < 288) {                                  // W1f: cf<16, ks<18
    const int cf = g / 18, ks = g % 18;
    _Float16* dst = &g_W1f[(size_t)(g < 0 ? 0 : (cf * 18 + ks)) * 64 * 8 + l * 8];
    const float* src = &W1[(size_t)(cf * 16 + r16) * DIN + ks * 32 + koff];
#pragma unroll
    for (int j = 0; j < 8; ++j) dst[j] = (_Float16)src[j];
  } else if (g < 416) {                           // W2f: cf<16, ks<8
    const int gg = g - 288, cf = gg / 8, ks = gg % 8;
    _Float16* dst = &g_W2f[(size_t)(cf * 8 + ks) * 64 * 8 + l * 8];
    const float* src = &W2[(size_t)(cf * 16 + r16) * HD + ks * 32 + koff];
#pragma unroll
    for (int j = 0; j < 8; ++j) dst[j] = (_Float16)src[j];
  } else if (g < 928) {                           // Wrzf: cf<32, ks<16, K=512 = [W_ih|W_hh]
    const int gg = g - 416, cf = gg / 16, ks = gg % 16;
    const int gr = (cf < 16) ? (cf * 16 + r16) : (256 + (cf - 16) * 16 + r16);
    const int k = ks * 32 + koff;                 // 0..511, 8-chunk never straddles 256
    const float* src = (k < 256) ? &W_ih[(size_t)gr * HD + k]
                                 : &W_hh[(size_t)gr * HD + (k - 256)];
    _Float16* dst = &g_Wrzf[(size_t)(cf * 16 + ks) * 64 * 8 + l * 8];
#pragma unroll
    for (int j = 0; j < 8; ++j) dst[j] = (_Float16)src[j];
  } else if (g < 1056) {                          // Wnxf: W_ih rows 512..767
    const int gg = g - 928, cf = gg / 8, ks = gg % 8;
    _Float16* dst = &g_Wnxf[(size_t)(cf * 8 + ks) * 64 * 8 + l * 8];
    const float* src = &W_ih[(size_t)(512 + cf * 16 + r16) * HD + ks * 32 + koff];
#pragma unroll
    for (int j = 0; j < 8; ++j) dst[j] = (_Float16)src[j];
  } else if (g < 1184) {                          // Wnhf: W_hh rows 512..767
    const int gg = g - 1056, cf = gg / 8, ks = gg % 8;
    _Float16* dst = &g_Wnhf[(size_t)(cf * 8 + ks) * 64 * 8 + l * 8];
    const float* src = &W_hh[(size_t)(512 + cf * 16 + r16) * HD + ks * 32 + koff];
#pragma unroll
    for (int j = 0; j < 8; ++j) dst[j] = (_Float16)src[j];
  }
}

// -------------------- fused edge MLP (MFMA fp16) + scatter-add --------------------
// 64 edges/block, 4 waves; wave w owns ALL 64 edges x cols [64w,64w+64).
// A staged per-K-slice (256/256/64) into one 34KB buffer -> 4 blocks/CU.
__global__ __launch_bounds__(256, 4) void edge_kernel(
    const float* __restrict__ h, const int* __restrict__ ei,
    const float* __restrict__ eattr,
    const float* __restrict__ b1, const float* __restrict__ b2,
    float* __restrict__ agg)
{
  __shared__ _Float16 A[64 * ASTRIDE];   // 33792 B, reused per slice and for hid
  __shared__ int rowL[64], colL[64];

  const int t   = threadIdx.x;
  const int w   = t >> 6;
  const int l   = t & 63;
  const int l15 = l & 15;
  const int lg  = l >> 4;
  const int e0  = blockIdx.x * 64;

  if (t < 64) { rowL[t] = ei[e0 + t]; colL[t] = ei[NE + e0 + t]; }

  f32x4 acc[4][4];
#pragma unroll
  for (int m = 0; m < 4; ++m)
#pragma unroll
    for (int n = 0; n < 4; ++n) acc[m][n] = (f32x4){0.f, 0.f, 0.f, 0.f};

  const int afrag_base = l15 * ASTRIDE + lg * 8;   // + m*16*ASTRIDE + ks*32

  // ---- slices 0,1: h[row] / h[col], 8 K-steps each ----
#pragma unroll
  for (int s = 0; s < 2; ++s) {
    __syncthreads();
    const int* idxL = s == 0 ? rowL : colL;
#pragma unroll
    for (int i = 0; i < 16; ++i) {
      const int e = i * 4 + w;
      float4 v = ((const float4*)(h + (size_t)idxL[e] * HD))[l];
      *(h4*)&A[e * ASTRIDE + l * 4] = f2h4(v);
    }
    __syncthreads();
    for (int ks = 0; ks < 8; ++ks) {
      const int ksg = s * 8 + ks;
      h8 b[4];
#pragma unroll
      for (int n = 0; n < 4; ++n)
        b[n] = *(const h8*)&g_W1f[(size_t)(((w * 4 + n) * 18 + ksg) * 64 + l) * 8];
#pragma unroll
      for (int m = 0; m < 4; ++m) {
        const h8 a = *(const h8*)&A[afrag_base + m * 16 * ASTRIDE + ks * 32];
#pragma unroll
        for (int n = 0; n < 4; ++n)
          acc[m][n] = __builtin_amdgcn_mfma_f32_16x16x32_f16(a, b[n], acc[m][n], 0, 0, 0);
      }
    }
  }

  // ---- slice 2: eattr, 2 K-steps ----
  __syncthreads();
#pragma unroll
  for (int i = 0; i < 4; ++i) {
    const int e = i * 16 + w * 4 + lg;
    float4 v = ((const float4*)(eattr + (size_t)(e0 + e) * EDIM))[l15];
    *(h4*)&A[e * ASTRIDE + l15 * 4] = f2h4(v);
  }
  __syncthreads();
  for (int ks = 0; ks < 2; ++ks) {
    const int ksg = 16 + ks;
    h8 b[4];
#pragma unroll
    for (int n = 0; n < 4; ++n)
      b[n] = *(const h8*)&g_W1f[(size_t)(((w * 4 + n) * 18 + ksg) * 64 + l) * 8];
#pragma unroll
    for (int m = 0; m < 4; ++m) {
      const h8 a = *(const h8*)&A[afrag_base + m * 16 * ASTRIDE + ks * 32];
#pragma unroll
      for (int n = 0; n < 4; ++n)
        acc[m][n] = __builtin_amdgcn_mfma_f32_16x16x32_f16(a, b[n], acc[m][n], 0, 0, 0);
    }
  }

  // ---- hid = relu(acc + b1) -> LDS fp16 (reuse A) ----
  __syncthreads();
#pragma unroll
  for (int n = 0; n < 4; ++n) {
    const int c = w * 64 + n * 16 + l15;
    const float bb = b1[c];
#pragma unroll
    for (int m = 0; m < 4; ++m)
#pragma unroll
      for (int r = 0; r < 4; ++r) {
        const int e = m * 16 + lg * 4 + r;
        float v = acc[m][n][r] + bb;
        v = v > 0.f ? v : 0.f;
        A[e * ASTRIDE + c] = (_Float16)v;
      }
  }
  __syncthreads();

  // ---- layer 2: 8 K-steps ----
  f32x4 acc2[4][4];
#pragma unroll
  for (int m = 0; m < 4; ++m)
#pragma unroll
    for (int n = 0; n < 4; ++n) acc2[m][n] = (f32x4){0.f, 0.f, 0.f, 0.f};

  for (int ks = 0; ks < 8; ++ks) {
    h8 b[4];
#pragma unroll
    for (int n = 0; n < 4; ++n)
      b[n] = *(const h8*)&g_W2f[(size_t)(((w * 4 + n) * 8 + ks) * 64 + l) * 8];
#pragma unroll
    for (int m = 0; m < 4; ++m) {
      const h8 a = *(const h8*)&A[afrag_base + m * 16 * ASTRIDE + ks * 32];
#pragma unroll
      for (int n = 0; n < 4; ++n)
        acc2[m][n] = __builtin_amdgcn_mfma_f32_16x16x32_f16(a, b[n], acc2[m][n], 0, 0, 0);
    }
  }

  // ---- scatter-add msg + b2 into agg ----
#pragma unroll
  for (int n = 0; n < 4; ++n) {
    const int c = w * 64 + n * 16 + l15;
    const float bb = b2[c];
#pragma unroll
    for (int m = 0; m < 4; ++m)
#pragma unroll
      for (int r = 0; r < 4; ++r) {
        const int e = m * 16 + lg * 4 + r;
        unsafeAtomicAdd(&agg[(size_t)rowL[e] * HD + c], acc2[m][n][r] + bb);
      }
  }
}

// -------------------- fused GRU update (MFMA fp16) --------------------
// block: 64 nodes x 64 gate-cols (c0); wave w owns nodes [16w,16w+16).
// r,z combined into one K=512 GEMM over [agg|h]; xn/hn separate K=256.
__global__ __launch_bounds__(256, 4) void gru_kernel(
    const float* __restrict__ h, const float* __restrict__ agg,
    const float* __restrict__ b_ih, const float* __restrict__ b_hh,
    float* __restrict__ out)
{
  __shared__ _Float16 A[64 * ASTRIDE];   // 33792 B

  const int t   = threadIdx.x;
  const int w   = t >> 6;
  const int l   = t & 63;
  const int l15 = l & 15;
  const int lg  = l >> 4;
  const int nb  = blockIdx.x * 64;
  const int c0  = blockIdx.y * 64;
  const int cf0 = c0 >> 4;

  f32x4 ar[4], az[4], ax[4], ah[4];
#pragma unroll
  for (int n = 0; n < 4; ++n) {
    ar[n] = (f32x4){0.f, 0.f, 0.f, 0.f}; az[n] = (f32x4){0.f, 0.f, 0.f, 0.f};
    ax[n] = (f32x4){0.f, 0.f, 0.f, 0.f}; ah[n] = (f32x4){0.f, 0.f, 0.f, 0.f};
  }

  const int afrag_base = (w * 16 + l15) * ASTRIDE + lg * 8;

#pragma unroll
  for (int s = 0; s < 2; ++s) {
    __syncthreads();
    const float* src = s == 0 ? agg : h;
#pragma unroll
    for (int i = 0; i < 16; ++i) {
      const int e = i * 4 + w;
      int node = nb + e; if (node >= NN) node = NN - 1;
      float4 v = ((const float4*)(src + (size_t)node * HD))[l];
      *(h4*)&A[e * ASTRIDE + l * 4] = f2h4(v);
    }
    __syncthreads();
    for (int ks = 0; ks < 8; ++ks) {
      const int ksg = s * 8 + ks;
      const h8 a = *(const h8*)&A[afrag_base + ks * 32];
      h8 br[4], bz[4], bn[4];
#pragma unroll
      for (int n = 0; n < 4; ++n) {
        br[n] = *(const h8*)&g_Wrzf[(size_t)(((cf0 + n) * 16 + ksg) * 64 + l) * 8];
        bz[n] = *(const h8*)&g_Wrzf[(size_t)(((16 + cf0 + n) * 16 + ksg) * 64 + l) * 8];
        bn[n] = (s == 0)
          ? *(const h8*)&g_Wnxf[(size_t)(((cf0 + n) * 8 + ks) * 64 + l) * 8]
          : *(const h8*)&g_Wnhf[(size_t)(((cf0 + n) * 8 + ks) * 64 + l) * 8];
      }
#pragma unroll
      for (int n = 0; n < 4; ++n) {
        ar[n] = __builtin_amdgcn_mfma_f32_16x16x32_f16(a, br[n], ar[n], 0, 0, 0);
        az[n] = __builtin_amdgcn_mfma_f32_16x16x32_f16(a, bz[n], az[n], 0, 0, 0);
        if (s == 0) ax[n] = __builtin_amdgcn_mfma_f32_16x16x32_f16(a, bn[n], ax[n], 0, 0, 0);
        else        ah[n] = __builtin_amdgcn_mfma_f32_16x16x32_f16(a, bn[n], ah[n], 0, 0, 0);
      }
    }
  }

  // ---- gates + output ----
#pragma unroll
  for (int n = 0; n < 4; ++n) {
    const int c = c0 + n * 16 + l15;
    const float br_ = b_ih[c] + b_hh[c];
    const float bz_ = b_ih[HD + c] + b_hh[HD + c];
    const float bxn = b_ih[2 * HD + c];
    const float bhn = b_hh[2 * HD + c];
#pragma unroll
    for (int r = 0; r < 4; ++r) {
      const int node = nb + w * 16 + lg * 4 + r;
      if (node < NN) {
        const float rg = 1.f / (1.f + __expf(-(ar[n][r] + br_)));
        const float zg = 1.f / (1.f + __expf(-(az[n][r] + bz_)));
        const float ng = tanhf(ax[n][r] + bxn + rg * (ah[n][r] + bhn));
        const float hv = h[(size_t)node * HD + c];
        out[(size_t)node * HD + c] = (1.f - zg) * ng + zg * hv;
      }
    }
  }
}

extern "C" void kernel_launch(void* const* d_in, const int* in_sizes, int n_in,
                              void* d_out, int out_size, void* d_ws, size_t ws_size,
                              hipStream_t stream)
{
  const float* h     = (const float*)d_in[0];
  const int*   ei    = (const int*)d_in[1];
  const float* eattr = (const float*)d_in[2];
  const float* W1    = (const float*)d_in[3];
  const float* b1    = (const float*)d_in[4];
  const float* W2    = (const float*)d_in[5];
  const float* b2    = (const float*)d_in[6];
  const float* W_ih  = (const float*)d_in[7];
  const float* b_ih  = (const float*)d_in[8];
  const float* W_hh  = (const float*)d_in[9];
  const float* b_hh  = (const float*)d_in[10];
  float* out = (float*)d_out;
  float* agg = (float*)d_ws;   // [NN][HD] f32 = 20.5 MB

  hipMemsetAsync(agg, 0, (size_t)NN * HD * sizeof(float), stream);
  cvt_kernel<<<(1184 * 64 + 255) / 256, 256, 0, stream>>>(W1, W2, W_ih, W_hh);
  edge_kernel<<<NE / 64, 256, 0, stream>>>(h, ei, eattr, b1, b2, agg);
  gru_kernel<<<dim3((NN + 63) / 64, HD / 64), 256, 0, stream>>>(h, agg, b_ih, b_hh, out);
}